// Round 22
// baseline (63.094 us; speedup 1.0000x reference)
//
#include <hip/hip_runtime.h>
#include <math.h>

#define NV 24
#define NB 8
#define NS 512
#define NTOK 4096       // NB*NS
#define H1 128
#define H2 64
#define SH1 256
#define SH2 128
#define IH 32
#define NP 576          // NV*NV

typedef short bf16x8 __attribute__((ext_vector_type(8)));
typedef float f32x4 __attribute__((ext_vector_type(4)));

__device__ __forceinline__ short f2bf(float f) {
    union { float f; unsigned u; } x; x.f = f;
    unsigned r = x.u + 0x7fffu + ((x.u >> 16) & 1u);   // RNE
    return (short)(r >> 16);
}

__device__ __forceinline__ float blk_reduce(float x, float* red, int t) {
#pragma unroll
    for (int o = 32; o > 0; o >>= 1) x += __shfl_xor(x, o);
    if ((t & 63) == 0) red[t >> 6] = x;
    __syncthreads();
    float r = red[0] + red[1] + red[2] + red[3];
    __syncthreads();
    return r;
}

// ---------------- ws layout (floats) ----------------
// [576,832) h1 | [960,1088) warm-scratch
// [1088,1280) partialS [8][24] | [1280,5888) partialG [8][576]
// [8192,106496) dataT | [106496,253952) sW1T | [253952,286720) sW2T
// [286720,360448) sW3T

// K1: 0..15 LDS-tiled coalesced data transpose; 16..77 repack structure
// weights; 78..205 warm pred/ind weights; 206..213 partial Gram + sums.
__global__ __launch_bounds__(256) void k_prep(
    const float* __restrict__ data, float* __restrict__ dataT,
    const float* __restrict__ sW1, const float* __restrict__ sW2,
    const float* __restrict__ sW3,
    float* __restrict__ sW1T, float* __restrict__ sW2T, float* __restrict__ sW3T,
    const float* __restrict__ mW1, const float* __restrict__ mW2,
    const float* __restrict__ iW1, const float* __restrict__ ib1,
    const float* __restrict__ iW2, const float* __restrict__ ib2,
    float* __restrict__ scratch,
    float* __restrict__ partialS, float* __restrict__ partialG) {
    __shared__ __align__(16) char L[25600];
    const int u = blockIdx.x, t = threadIdx.x;
    if (u < 16) {
        // ---- coalesced tile transpose: tokens [u*256, u*256+256) ----
        float* T = (float*)L;              // [256][25]
        const int n0 = u * 256;
#pragma unroll
        for (int it = 0; it < 24; ++it) {
            int idx = it * 256 + t;        // 0..6143
            T[(idx / 24) * 25 + (idx % 24)] = data[n0 * 24 + idx];
        }
        __syncthreads();
#pragma unroll
        for (int v = 0; v < 24; ++v)
            dataT[v * NTOK + n0 + t] = T[t * 25 + v];
        return;
    }
    if (u < 78) {
        float (*T)[65] = (float (*)[65])L;
        int rb = u - 16;
        const float* src; float* dst; int R, C, ti, tj;
        if (rb < 36)      { src = sW1; dst = sW1T; R = 576; C = 256; ti = rb >> 2;        tj = rb & 3; }
        else if (rb < 44) { src = sW2; dst = sW2T; R = 256; C = 128; ti = (rb - 36) >> 1; tj = (rb - 36) & 1; }
        else              { src = sW3; dst = sW3T; R = 128; C = 576; ti = (rb - 44) / 9;  tj = (rb - 44) % 9; }
        const int col = t & 63, rq = t >> 6;
#pragma unroll
        for (int i = 0; i < 16; ++i) {
            int row = i * 4 + rq;
            T[row][col] = src[(ti * 64 + row) * C + tj * 64 + col];
        }
        __syncthreads();
#pragma unroll
        for (int i = 0; i < 16; ++i) {
            int row = i * 4 + rq;
            dst[(tj * 64 + row) * R + ti * 64 + col] = T[col][row];
        }
        return;
    }
    if (u < 206) {
        // warm blocks (128): grid-stride float4 reads over pred/ind weights
        const int wb = u - 78;
        float acc = 0.f;
        const float4* srcs[6] = { (const float4*)mW1, (const float4*)mW2,
                                  (const float4*)iW1, (const float4*)ib1,
                                  (const float4*)iW2, (const float4*)ib2 };
        const int len4[6] = { NV * 23 * H1 / 4, NV * H1 * H2 / 4,
                              NP * 2 * IH / 4, NP * IH / 4, NP * IH / 4,
                              NP / 4 };
#pragma unroll
        for (int a = 0; a < 6; ++a) {
            const float4* p = srcs[a];
            const int n4 = len4[a];
            for (int idx = wb * 256 + t; idx < n4; idx += 128 * 256) {
                float4 v = p[idx];
                acc += v.x + v.y + v.z + v.w;
            }
        }
        float* red = (float*)L;
        acc = blk_reduce(acc, red, t);
        if (t == 0) scratch[wb] = acc;   // defeat DCE
        return;
    }
    // ---- gram blocks (8): block gb owns s in [gb*64, gb*64+64) ----
    const int gb = u - 206;
    float* avgL = (float*)L;             // 64*24 floats
    const int s0 = gb * 64;
    for (int idx = t; idx < 64 * NV; idx += 256) {
        float a = 0.f;
#pragma unroll
        for (int b = 0; b < NB; ++b)
            a += data[(b * NS + s0) * NV + idx];
        avgL[idx] = a * 0.125f;
    }
    __syncthreads();
    if (t < NV) {
        float s = 0.f;
        for (int ss = 0; ss < 64; ++ss) s += avgL[ss * NV + t];
        partialS[gb * NV + t] = s;
    }
    for (int p = t; p < NP; p += 256) {
        int i = p / NV, j = p % NV;
        float g = 0.f;
        for (int ss = 0; ss < 64; ++ss)
            g = fmaf(avgL[ss * NV + i], avgL[ss * NV + j], g);
        partialG[gb * NP + p] = g;
    }
}

// K2: layer1 -- one block per output (256 blocks). Reduces Gram partials
// inline (cov = G - S_i*S_j/NS), builds corr, then its 576-dot.
__global__ __launch_bounds__(256) void k_adj1(
    const float* __restrict__ partialG, const float* __restrict__ partialS,
    const float* __restrict__ sW1T, const float* __restrict__ sb1,
    float* __restrict__ h1out) {
    __shared__ float corrL[NP];
    __shared__ float stdL[NV];
    __shared__ float Sv[NV];
    __shared__ float red[256];
    const int o = blockIdx.x, t = threadIdx.x;
    if (t < NV) {
        float s = 0.f;
#pragma unroll
        for (int b = 0; b < NB; ++b) s += partialS[b * NV + t];
        Sv[t] = s;
    }
    __syncthreads();
    for (int k = t; k < NP; k += 256) {
        float g = 0.f;
#pragma unroll
        for (int b = 0; b < NB; ++b) g += partialG[b * NP + k];
        int i = k / NV, j = k % NV;
        corrL[k] = g - Sv[i] * Sv[j] * (1.f / NS);   // cov
    }
    __syncthreads();
    if (t < NV) stdL[t] = sqrtf(corrL[t * (NV + 1)]);
    __syncthreads();
    for (int k = t; k < NP; k += 256) {
        int i = k / NV, j = k % NV;
        float q = fabsf(corrL[k] / (stdL[i] * stdL[j]));
        if (isnan(q)) q = 0.f;
        if (i == j) q = 0.f;
        corrL[k] = q;
    }
    __syncthreads();
    const float* w = sW1T + o * 576;
    float w0 = w[t], w1 = w[256 + t];
    float w2 = (t < 64) ? w[512 + t] : 0.f;
    float c2 = (t < 64) ? corrL[512 + t] : 0.f;
    float a = corrL[t] * w0 + corrL[256 + t] * w1 + c2 * w2;
    a = blk_reduce(a, red, t);
    if (t == 0) h1out[o] = fmaxf(a + sb1[o], 0.f);
}

// K3: blocks 0..767 = MFMA pred (inline h2 from h1, inline adj column,
// chunk-0 writes out_adj column v); 768..1343 = ind (coalesced dataT rows).
__global__ __launch_bounds__(256) void k_predind(
    const float* __restrict__ data,
    const float* __restrict__ mW1, const float* __restrict__ mb1,
    const float* __restrict__ mW2, const float* __restrict__ mb2,
    const float* __restrict__ mW3, const float* __restrict__ mb3,
    const float* __restrict__ h1, const float* __restrict__ sW2T,
    const float* __restrict__ sb2, const float* __restrict__ sW3T,
    const float* __restrict__ sb3,
    float* __restrict__ out_adj, float* __restrict__ out_pred,
    const float* __restrict__ dataT,
    const float* __restrict__ iW1, const float* __restrict__ ib1,
    const float* __restrict__ iW2, const float* __restrict__ ib2,
    float* __restrict__ out_ind) {
    __shared__ __align__(16) char L[34816];
    const int bx = blockIdx.x;
    const int t = threadIdx.x;

    if (bx < 768) {
        // ---------------- pred ----------------
        const int v = bx % NV;
        const int chunk = bx / NV;

        float* h1L  = (float*)L;          // 256
        float* h2L  = (float*)L + 256;    // 128
        float* P3   = (float*)L + 384;    // 192
        float* maskL = (float*)L + 576;   // 24

        h1L[t] = h1[t];
        __syncthreads();
        // inline h2: thread t<128 computes h2[t] over contiguous sW2T row
        if (t < SH2) {
            const float4* wr = (const float4*)(sW2T + t * 256);
            float a = sb2[t];
#pragma unroll
            for (int q = 0; q < 64; ++q) {
                float4 w = wr[q];
                a = fmaf(h1L[q * 4 + 0], w.x, a);
                a = fmaf(h1L[q * 4 + 1], w.y, a);
                a = fmaf(h1L[q * 4 + 2], w.z, a);
                a = fmaf(h1L[q * 4 + 3], w.w, a);
            }
            h2L[t] = fmaxf(a, 0.f);
        }
        __syncthreads();
        // inline adj column v: partial dots P3[r][kq]
        {
            const int r3 = t >> 3, kq3 = t & 7;
            if (r3 < NV) {
                float a = 0.f;
                if (r3 < v) {
                    const float* w = sW3T + (r3 * NV + v) * 128 + kq3 * 16;
                    const float* hp2 = h2L + kq3 * 16;
#pragma unroll
                    for (int kk = 0; kk < 16; ++kk)
                        a = fmaf(hp2[kk], w[kk], a);
                }
                P3[r3 * 8 + kq3] = a;
            }
        }
        __syncthreads();
        if (t < NV) {
            float s = 0.f;
#pragma unroll
            for (int q = 0; q < 8; ++q) s += P3[t * 8 + q];
            float sg = 1.f / (1.f + expf(-(s + sb3[t * NV + v])));
            maskL[t] = (t < v && sg > 0.5f) ? 1.f : 0.f;
            if (chunk == 0)
                out_adj[t * NV + v] = (t < v) ? sg : 0.f;
        }
        __syncthreads();
        bool hp = false;
#pragma unroll
        for (int r = 0; r < NV; ++r) hp = hp || (maskL[r] > 0.5f);
        float pm_reg = 0.f;
        if (t < 184) {
            int k = t >> 3;
            int src1 = k + (k >= v ? 1 : 0);
            pm_reg = maskL[src1];
        }
        __syncthreads();   // all maskL reads done before L is reused

        if (!hp) {
            if (t < 128) {
                int tok = chunk * 128 + t;
                out_pred[tok * NV + v] = data[tok * NV + v];
            }
            return;
        }
        short* Xl = (short*)L;
        short* WH = (short*)(L + 10240);
        short* W1B = WH;
        short* W2B = WH + 4096;
        short* Hl = WH;

        if (t < 128) {
            int tok = chunk * 128 + t;
            const float4* dr4 = (const float4*)(data + tok * NV);
            float d[24];
#pragma unroll
            for (int q = 0; q < 6; ++q) {
                float4 uu = dr4[q];
                d[q * 4 + 0] = uu.x; d[q * 4 + 1] = uu.y; d[q * 4 + 2] = uu.z; d[q * 4 + 3] = uu.w;
            }
            short xr[32];
#pragma unroll
            for (int j = 0; j < 23; ++j) {
                int src = j + (j >= v ? 1 : 0);
                xr[j] = f2bf(d[src]);
            }
            xr[23] = f2bf(1.0f);
#pragma unroll
            for (int j = 24; j < 32; ++j) xr[j] = 0;
            short* xp = Xl + t * 40;
#pragma unroll
            for (int q = 0; q < 4; ++q)
                *(bf16x8*)(xp + q * 8) = *(bf16x8*)(xr + q * 8);
        }
        if (t < 184) {
            int k = t >> 3, h8 = (t & 7) * 16;
            const float4* wr = (const float4*)(mW1 + (v * 23 + k) * 128 + h8);
            float wv[16];
#pragma unroll
            for (int q = 0; q < 4; ++q) {
                float4 uu = wr[q];
                wv[q * 4 + 0] = uu.x; wv[q * 4 + 1] = uu.y;
                wv[q * 4 + 2] = uu.z; wv[q * 4 + 3] = uu.w;
            }
            int kb = (k >> 3) & 3, e = k & 7;
#pragma unroll
            for (int q = 0; q < 16; ++q) {
                int h = h8 + q;
                int nt = h >> 4, nn = h & 15;
                W1B[((nt * 4 + kb) * 16 + nn) * 8 + e] = f2bf(wv[q] * pm_reg);
            }
        } else if (t < 200) {
            int h8 = (t - 184) * 8;
            const float4* br = (const float4*)(mb1 + v * 128 + h8);
            float bv[8];
#pragma unroll
            for (int q = 0; q < 2; ++q) {
                float4 uu = br[q];
                bv[q * 4 + 0] = uu.x; bv[q * 4 + 1] = uu.y;
                bv[q * 4 + 2] = uu.z; bv[q * 4 + 3] = uu.w;
            }
#pragma unroll
            for (int q = 0; q < 8; ++q) {
                int h = h8 + q;
                int nt = h >> 4, nn = h & 15;
                W1B[((nt * 4 + 2) * 16 + nn) * 8 + 7] = f2bf(bv[q]);   // k=23
            }
        }
        if (t < 128) {
            int nt = t >> 4, nn = t & 15;
#pragma unroll
            for (int e = 0; e < 8; ++e)
                W1B[((nt * 4 + 3) * 16 + nn) * 8 + e] = 0;
        }
        {
            int k = t >> 1, n0 = (t & 1) * 32;
            const float4* wr = (const float4*)(mW2 + (v * 128 + k) * 64 + n0);
            float wv[32];
#pragma unroll
            for (int q = 0; q < 8; ++q) {
                float4 uu = wr[q];
                wv[q * 4 + 0] = uu.x; wv[q * 4 + 1] = uu.y;
                wv[q * 4 + 2] = uu.z; wv[q * 4 + 3] = uu.w;
            }
            int s = k >> 5, kb = (k >> 3) & 3, e = k & 7;
#pragma unroll
            for (int q = 0; q < 32; ++q) {
                int n = n0 + q;
                int nt = n >> 4, nn = n & 15;
                W2B[(((s * 4 + nt) * 4 + kb) * 16 + nn) * 8 + e] = f2bf(wv[q]);
            }
        }
        __syncthreads();

        const int lane = t & 63;
        const int wid = t >> 6;
        const int ml = lane & 15;
        const int kb = lane >> 4;
        short* Hw = Hl + wid * 2048;

        bf16x8 w1f[8], w2f[16];
#pragma unroll
        for (int nt = 0; nt < 8; ++nt)
            w1f[nt] = *(bf16x8*)(W1B + (nt * 64 + lane) * 8);
#pragma unroll
        for (int q = 0; q < 16; ++q)
            w2f[q] = *(bf16x8*)(W2B + (q * 64 + lane) * 8);

        float b2r[4], w3r[4];
#pragma unroll
        for (int nt = 0; nt < 4; ++nt) {
            b2r[nt] = mb2[v * 64 + nt * 16 + ml];
            w3r[nt] = mW3[v * 64 + nt * 16 + ml];
        }
        float b3v = mb3[v];

        __syncthreads();   // W1B/W2B fully read before Hl (aliased) written

#pragma unroll
        for (int mt = 0; mt < 2; ++mt) {
            int lt = wid * 32 + mt * 16 + ml;
            bf16x8 a1 = *(bf16x8*)(Xl + lt * 40 + kb * 8);
            f32x4 c1[8] = {};
#pragma unroll
            for (int nt = 0; nt < 8; ++nt)
                c1[nt] = __builtin_amdgcn_mfma_f32_16x16x32_bf16(a1, w1f[nt], c1[nt], 0, 0, 0);
#pragma unroll
            for (int nt = 0; nt < 8; ++nt) {
#pragma unroll
                for (int r = 0; r < 4; ++r) {
                    int m = kb * 4 + r;
                    int h = nt * 16 + ml;
                    int bo = (m * 256 + h * 2) ^ ((m & 7) << 4);
                    *(short*)((char*)Hw + bo) = f2bf(fmaxf(c1[nt][r], 0.f));
                }
            }
            f32x4 c2[4] = {};
#pragma unroll
            for (int s = 0; s < 4; ++s) {
                int c0 = s * 32 + kb * 8;
                int bo = (ml * 256 + c0 * 2) ^ ((ml & 7) << 4);
                bf16x8 a2 = *(bf16x8*)((char*)Hw + bo);
#pragma unroll
                for (int nt = 0; nt < 4; ++nt)
                    c2[nt] = __builtin_amdgcn_mfma_f32_16x16x32_bf16(a2, w2f[s * 4 + nt], c2[nt], 0, 0, 0);
            }
            float sacc[4] = {0.f, 0.f, 0.f, 0.f};
#pragma unroll
            for (int nt = 0; nt < 4; ++nt) {
#pragma unroll
                for (int r = 0; r < 4; ++r)
                    sacc[r] += fmaxf(c2[nt][r] + b2r[nt], 0.f) * w3r[nt];
            }
#pragma unroll
            for (int o = 1; o < 16; o <<= 1) {
#pragma unroll
                for (int r = 0; r < 4; ++r)
                    sacc[r] += __shfl_xor(sacc[r], o);
            }
            if (ml == 0) {
                int tokb = chunk * 128 + wid * 32 + mt * 16 + kb * 4;
#pragma unroll
                for (int r = 0; r < 4; ++r)
                    out_pred[(tokb + r) * NV + v] = sacc[r] + b3v;
            }
        }
    } else {
        // ---------------- ind ----------------
        int p = bx - 768;
        int i = p / NV, j = p % NV;
        float* red = (float*)L;
        float* wl = (float*)L + 256;
        if (t < IH) {
            wl[t]      = iW1[p * 2 * IH + t];
            wl[32 + t] = iW1[p * 2 * IH + IH + t];
            wl[64 + t] = ib1[p * IH + t];
            wl[96 + t] = iW2[p * IH + t];
        }
        __syncthreads();
        float b2v = ib2[p];
        const float* di_p = dataT + i * NTOK;
        const float* dj_p = dataT + j * NTOK;
        float di[16], dj[16], s[16];
#pragma unroll
        for (int q = 0; q < 16; ++q) {
            di[q] = di_p[q * 256 + t];
            dj[q] = dj_p[q * 256 + t];
            s[q] = b2v;
        }
#pragma unroll 4
        for (int h = 0; h < IH; ++h) {
            float w0 = wl[h], w1 = wl[32 + h], bb = wl[64 + h], w2 = wl[96 + h];
#pragma unroll
            for (int q = 0; q < 16; ++q) {
                float a = fmaf(di[q], w0, fmaf(dj[q], w1, bb));
                a = fmaxf(a, 0.f);
                s[q] = fmaf(a, w2, s[q]);
            }
        }
        float acc = 0.f;
#pragma unroll
        for (int q = 0; q < 16; ++q) acc += 1.f / (1.f + expf(-s[q]));
        __syncthreads();
        red[t] = acc;
        __syncthreads();
        for (int st = 128; st > 0; st >>= 1) {
            if (t < st) red[t] += red[t + st];
            __syncthreads();
        }
        if (t == 0) out_ind[p] = red[0] * (1.f / NTOK);
    }
}

extern "C" void kernel_launch(void* const* d_in, const int* in_sizes, int n_in,
                              void* d_out, int out_size, void* d_ws, size_t ws_size,
                              hipStream_t stream) {
    const float* data = (const float*)d_in[0];
    const float* sW1 = (const float*)d_in[1];
    const float* sb1 = (const float*)d_in[2];
    const float* sW2 = (const float*)d_in[3];
    const float* sb2 = (const float*)d_in[4];
    const float* sW3 = (const float*)d_in[5];
    const float* sb3 = (const float*)d_in[6];
    const float* mW1 = (const float*)d_in[7];
    const float* mb1 = (const float*)d_in[8];
    const float* mW2 = (const float*)d_in[9];
    const float* mb2 = (const float*)d_in[10];
    const float* mW3 = (const float*)d_in[11];
    const float* mb3 = (const float*)d_in[12];
    const float* iW1 = (const float*)d_in[13];
    const float* ib1 = (const float*)d_in[14];
    const float* iW2 = (const float*)d_in[15];
    const float* ib2 = (const float*)d_in[16];

    float* out = (float*)d_out;
    float* ws = (float*)d_ws;
    float* ws_h1 = ws + 576;
    float* ws_scratch = ws + 960;
    float* ws_pS = ws + 1088;
    float* ws_pG = ws + 1280;
    float* ws_dataT = ws + 8192;
    float* ws_sW1T = ws + 106496;
    float* ws_sW2T = ws + 253952;
    float* ws_sW3T = ws + 286720;

    k_prep<<<dim3(214), dim3(256), 0, stream>>>(data, ws_dataT, sW1, sW2, sW3,
                                                ws_sW1T, ws_sW2T, ws_sW3T,
                                                mW1, mW2, iW1, ib1, iW2, ib2,
                                                ws_scratch, ws_pS, ws_pG);
    k_adj1<<<dim3(SH1), dim3(256), 0, stream>>>(ws_pG, ws_pS, ws_sW1T, sb1, ws_h1);
    k_predind<<<dim3(768 + NP), dim3(256), 0, stream>>>(
        data, mW1, mb1, mW2, mb2, mW3, mb3, ws_h1, ws_sW2T, sb2, ws_sW3T, sb3,
        out, out + NP, ws_dataT, iW1, ib1, iW2, ib2, out + NP + NTOK * NV);
}

// Round 23
// 42.189 us; speedup vs baseline: 1.4955x; 1.4955x over previous
//
#include <hip/hip_runtime.h>
#include <math.h>

#define NV 24
#define NB 8
#define NS 512
#define NTOK 4096       // NB*NS
#define H1 128
#define H2 64
#define SH1 256
#define SH2 128
#define IH 32
#define NP 576          // NV*NV

typedef short bf16x8 __attribute__((ext_vector_type(8)));
typedef float f32x4 __attribute__((ext_vector_type(4)));

__device__ __forceinline__ short f2bf(float f) {
    union { float f; unsigned u; } x; x.f = f;
    unsigned r = x.u + 0x7fffu + ((x.u >> 16) & 1u);   // RNE
    return (short)(r >> 16);
}

__device__ __forceinline__ float blk_reduce(float x, float* red, int t) {
#pragma unroll
    for (int o = 32; o > 0; o >>= 1) x += __shfl_xor(x, o);
    if ((t & 63) == 0) red[t >> 6] = x;
    __syncthreads();
    float r = red[0] + red[1] + red[2] + red[3];
    __syncthreads();
    return r;
}

// ---------------- ws layout (floats) ----------------
// [576,832) h1 | [832,960) h2 | [960,1088) warm-scratch
// [1088,1280) partialS [8][24] | [1280,5888) partialG [8][576]
// [8192,106496) dataT | [106496,253952) sW1T | [253952,286720) sW2T
// [286720,360448) sW3T

// K1: 0..383 transpose data; 384..445 repack structure weights;
// 446..573 warm pred/ind weights; 574..581 partial Gram + sums (cov inputs).
__global__ __launch_bounds__(256) void k_prep(
    const float* __restrict__ data, float* __restrict__ dataT,
    const float* __restrict__ sW1, const float* __restrict__ sW2,
    const float* __restrict__ sW3,
    float* __restrict__ sW1T, float* __restrict__ sW2T, float* __restrict__ sW3T,
    const float* __restrict__ mW1, const float* __restrict__ mW2,
    const float* __restrict__ iW1, const float* __restrict__ ib1,
    const float* __restrict__ iW2,
    float* __restrict__ scratch,
    float* __restrict__ partialS, float* __restrict__ partialG) {
    __shared__ __align__(16) char L[16900];
    const int u = blockIdx.x, t = threadIdx.x;
    if (u < 384) {
        int idx = u * 256 + t;
        int n = idx / NV, v = idx % NV;
        dataT[v * NTOK + n] = data[idx];
        return;
    }
    if (u < 446) {
        float (*T)[65] = (float (*)[65])L;
        int rb = u - 384;
        const float* src; float* dst; int R, C, ti, tj;
        if (rb < 36)      { src = sW1; dst = sW1T; R = 576; C = 256; ti = rb >> 2;        tj = rb & 3; }
        else if (rb < 44) { src = sW2; dst = sW2T; R = 256; C = 128; ti = (rb - 36) >> 1; tj = (rb - 36) & 1; }
        else              { src = sW3; dst = sW3T; R = 128; C = 576; ti = (rb - 44) / 9;  tj = (rb - 44) % 9; }
        const int col = t & 63, rq = t >> 6;
#pragma unroll
        for (int i = 0; i < 16; ++i) {
            int row = i * 4 + rq;
            T[row][col] = src[(ti * 64 + row) * C + tj * 64 + col];
        }
        __syncthreads();
#pragma unroll
        for (int i = 0; i < 16; ++i) {
            int row = i * 4 + rq;
            dst[(tj * 64 + row) * R + ti * 64 + col] = T[col][row];
        }
        return;
    }
    if (u < 574) {
        // warm blocks (128): grid-stride float4 reads over pred/ind weights
        const int wb = u - 446;
        float acc = 0.f;
        const float4* srcs[5] = { (const float4*)mW1, (const float4*)mW2,
                                  (const float4*)iW1, (const float4*)ib1,
                                  (const float4*)iW2 };
        const int len4[5] = { NV * 23 * H1 / 4, NV * H1 * H2 / 4,
                              NP * 2 * IH / 4, NP * IH / 4, NP * IH / 4 };
#pragma unroll
        for (int a = 0; a < 5; ++a) {
            const float4* p = srcs[a];
            const int n4 = len4[a];
            for (int idx = wb * 256 + t; idx < n4; idx += 128 * 256) {
                float4 v = p[idx];
                acc += v.x + v.y + v.z + v.w;
            }
        }
        float* red = (float*)L;
        acc = blk_reduce(acc, red, t);
        if (t == 0) scratch[wb] = acc;   // defeat DCE
        return;
    }
    // ---- gram blocks (8): block gb owns s in [gb*64, gb*64+64) ----
    const int gb = u - 574;
    float* avgL = (float*)L;             // 64*24 floats = 6 KB
    const int s0 = gb * 64;
    for (int idx = t; idx < 64 * NV; idx += 256) {
        float a = 0.f;
#pragma unroll
        for (int b = 0; b < NB; ++b)
            a += data[(b * NS + s0) * NV + idx];
        avgL[idx] = a * 0.125f;
    }
    __syncthreads();
    if (t < NV) {
        float s = 0.f;
        for (int ss = 0; ss < 64; ++ss) s += avgL[ss * NV + t];
        partialS[gb * NV + t] = s;
    }
    for (int p = t; p < NP; p += 256) {
        int i = p / NV, j = p % NV;
        float g = 0.f;
        for (int ss = 0; ss < 64; ++ss)
            g = fmaf(avgL[ss * NV + i], avgL[ss * NV + j], g);
        partialG[gb * NP + p] = g;
    }
}

// K2: layer1 -- one block per output (256 blocks). Reduces the 8 Gram
// partials inline (cov = G - S_i*S_j/NS), builds corr, then its 576-dot.
__global__ __launch_bounds__(256) void k_adj1(
    const float* __restrict__ partialG, const float* __restrict__ partialS,
    const float* __restrict__ sW1T, const float* __restrict__ sb1,
    float* __restrict__ h1out) {
    __shared__ float corrL[NP];
    __shared__ float stdL[NV];
    __shared__ float Sv[NV];
    __shared__ float red[256];
    const int o = blockIdx.x, t = threadIdx.x;
    if (t < NV) {
        float s = 0.f;
#pragma unroll
        for (int b = 0; b < NB; ++b) s += partialS[b * NV + t];
        Sv[t] = s;
    }
    __syncthreads();
    for (int k = t; k < NP; k += 256) {
        float g = 0.f;
#pragma unroll
        for (int b = 0; b < NB; ++b) g += partialG[b * NP + k];
        int i = k / NV, j = k % NV;
        corrL[k] = g - Sv[i] * Sv[j] * (1.f / NS);   // cov
    }
    __syncthreads();
    if (t < NV) stdL[t] = sqrtf(corrL[t * (NV + 1)]);
    __syncthreads();
    for (int k = t; k < NP; k += 256) {
        int i = k / NV, j = k % NV;
        float q = fabsf(corrL[k] / (stdL[i] * stdL[j]));
        if (isnan(q)) q = 0.f;
        if (i == j) q = 0.f;
        corrL[k] = q;
    }
    __syncthreads();
    const float* w = sW1T + o * 576;
    float w0 = w[t], w1 = w[256 + t];
    float w2 = (t < 64) ? w[512 + t] : 0.f;
    float c2 = (t < 64) ? corrL[512 + t] : 0.f;
    float a = corrL[t] * w0 + corrL[256 + t] * w1 + c2 * w2;
    a = blk_reduce(a, red, t);
    if (t == 0) h1out[o] = fmaxf(a + sb1[o], 0.f);
}

// K3: layer2 -- 128 blocks x 256 threads, one k per thread.
__global__ __launch_bounds__(256) void k_adj2(
    const float* __restrict__ h1, const float* __restrict__ sW2T,
    const float* __restrict__ sb2, float* __restrict__ h2out) {
    __shared__ float red[256];
    const int o = blockIdx.x, t = threadIdx.x;
    float a = h1[t] * sW2T[o * 256 + t];
    a = blk_reduce(a, red, t);
    if (t == 0) h2out[o] = fmaxf(a + sb2[o], 0.f);
}

// K4: blocks 0..767 = MFMA pred (computes its own adj column from h2);
// 768..1343 = ind (coalesced dataT rows); 1344..1919 = adj outputs.
__global__ __launch_bounds__(256) void k_predind(
    const float* __restrict__ data,
    const float* __restrict__ mW1, const float* __restrict__ mb1,
    const float* __restrict__ mW2, const float* __restrict__ mb2,
    const float* __restrict__ mW3, const float* __restrict__ mb3,
    const float* __restrict__ h2, const float* __restrict__ sW3T,
    const float* __restrict__ sb3,
    float* __restrict__ out_adj, float* __restrict__ out_pred,
    const float* __restrict__ dataT,
    const float* __restrict__ iW1, const float* __restrict__ ib1,
    const float* __restrict__ iW2, const float* __restrict__ ib2,
    float* __restrict__ out_ind) {
    __shared__ __align__(16) char L[34816];
    const int bx = blockIdx.x;
    const int t = threadIdx.x;

    if (bx < 768) {
        // ---------------- pred ----------------
        const int v = bx % NV;
        const int chunk = bx / NV;

        // inline adj column v: P3[r][kq] partial dots, then sigmoid mask
        float* P3 = (float*)L;            // 24*8
        float* maskL = (float*)L + 192;   // 24
        {
            const int r3 = t >> 3, kq3 = t & 7;
            if (r3 < NV) {
                float a = 0.f;
                if (r3 < v) {
                    const float* w = sW3T + (r3 * NV + v) * 128 + kq3 * 16;
                    const float* hp2 = h2 + kq3 * 16;
#pragma unroll
                    for (int kk = 0; kk < 16; ++kk)
                        a = fmaf(hp2[kk], w[kk], a);
                }
                P3[r3 * 8 + kq3] = a;
            }
        }
        __syncthreads();
        if (t < NV) {
            float s = 0.f;
#pragma unroll
            for (int q = 0; q < 8; ++q) s += P3[t * 8 + q];
            float sg = 1.f / (1.f + expf(-(s + sb3[t * NV + v])));
            maskL[t] = (t < v && sg > 0.5f) ? 1.f : 0.f;
        }
        __syncthreads();
        bool hp = false;
#pragma unroll
        for (int r = 0; r < NV; ++r) hp = hp || (maskL[r] > 0.5f);
        // per-thread pm for W1 staging, read BEFORE L is overwritten
        float pm_reg = 0.f;
        if (t < 184) {
            int k = t >> 3;
            int src1 = k + (k >= v ? 1 : 0);
            pm_reg = maskL[src1];
        }
        __syncthreads();   // all maskL reads done before Xl staging writes L

        if (!hp) {
            if (t < 128) {
                int tok = chunk * 128 + t;
                out_pred[tok * NV + v] = data[tok * NV + v];
            }
            return;
        }
        short* Xl = (short*)L;
        short* WH = (short*)(L + 10240);
        short* W1B = WH;
        short* W2B = WH + 4096;
        short* Hl = WH;

        if (t < 128) {
            int tok = chunk * 128 + t;
            const float4* dr4 = (const float4*)(data + tok * NV);
            float d[24];
#pragma unroll
            for (int q = 0; q < 6; ++q) {
                float4 uu = dr4[q];
                d[q * 4 + 0] = uu.x; d[q * 4 + 1] = uu.y; d[q * 4 + 2] = uu.z; d[q * 4 + 3] = uu.w;
            }
            short xr[32];
#pragma unroll
            for (int j = 0; j < 23; ++j) {
                int src = j + (j >= v ? 1 : 0);
                xr[j] = f2bf(d[src]);
            }
            xr[23] = f2bf(1.0f);
#pragma unroll
            for (int j = 24; j < 32; ++j) xr[j] = 0;
            short* xp = Xl + t * 40;
#pragma unroll
            for (int q = 0; q < 4; ++q)
                *(bf16x8*)(xp + q * 8) = *(bf16x8*)(xr + q * 8);
        }
        if (t < 184) {
            int k = t >> 3, h8 = (t & 7) * 16;
            const float4* wr = (const float4*)(mW1 + (v * 23 + k) * 128 + h8);
            float wv[16];
#pragma unroll
            for (int q = 0; q < 4; ++q) {
                float4 uu = wr[q];
                wv[q * 4 + 0] = uu.x; wv[q * 4 + 1] = uu.y;
                wv[q * 4 + 2] = uu.z; wv[q * 4 + 3] = uu.w;
            }
            int kb = (k >> 3) & 3, e = k & 7;
#pragma unroll
            for (int q = 0; q < 16; ++q) {
                int h = h8 + q;
                int nt = h >> 4, nn = h & 15;
                W1B[((nt * 4 + kb) * 16 + nn) * 8 + e] = f2bf(wv[q] * pm_reg);
            }
        } else if (t < 200) {
            int h8 = (t - 184) * 8;
            const float4* br = (const float4*)(mb1 + v * 128 + h8);
            float bv[8];
#pragma unroll
            for (int q = 0; q < 2; ++q) {
                float4 uu = br[q];
                bv[q * 4 + 0] = uu.x; bv[q * 4 + 1] = uu.y;
                bv[q * 4 + 2] = uu.z; bv[q * 4 + 3] = uu.w;
            }
#pragma unroll
            for (int q = 0; q < 8; ++q) {
                int h = h8 + q;
                int nt = h >> 4, nn = h & 15;
                W1B[((nt * 4 + 2) * 16 + nn) * 8 + 7] = f2bf(bv[q]);   // k=23
            }
        }
        if (t < 128) {
            int nt = t >> 4, nn = t & 15;
#pragma unroll
            for (int e = 0; e < 8; ++e)
                W1B[((nt * 4 + 3) * 16 + nn) * 8 + e] = 0;
        }
        {
            int k = t >> 1, n0 = (t & 1) * 32;
            const float4* wr = (const float4*)(mW2 + (v * 128 + k) * 64 + n0);
            float wv[32];
#pragma unroll
            for (int q = 0; q < 8; ++q) {
                float4 uu = wr[q];
                wv[q * 4 + 0] = uu.x; wv[q * 4 + 1] = uu.y;
                wv[q * 4 + 2] = uu.z; wv[q * 4 + 3] = uu.w;
            }
            int s = k >> 5, kb = (k >> 3) & 3, e = k & 7;
#pragma unroll
            for (int q = 0; q < 32; ++q) {
                int n = n0 + q;
                int nt = n >> 4, nn = n & 15;
                W2B[(((s * 4 + nt) * 4 + kb) * 16 + nn) * 8 + e] = f2bf(wv[q]);
            }
        }
        __syncthreads();

        const int lane = t & 63;
        const int wid = t >> 6;
        const int ml = lane & 15;
        const int kb = lane >> 4;
        short* Hw = Hl + wid * 2048;

        bf16x8 w1f[8], w2f[16];
#pragma unroll
        for (int nt = 0; nt < 8; ++nt)
            w1f[nt] = *(bf16x8*)(W1B + (nt * 64 + lane) * 8);
#pragma unroll
        for (int q = 0; q < 16; ++q)
            w2f[q] = *(bf16x8*)(W2B + (q * 64 + lane) * 8);

        float b2r[4], w3r[4];
#pragma unroll
        for (int nt = 0; nt < 4; ++nt) {
            b2r[nt] = mb2[v * 64 + nt * 16 + ml];
            w3r[nt] = mW3[v * 64 + nt * 16 + ml];
        }
        float b3v = mb3[v];

        __syncthreads();   // W1B/W2B fully read before Hl (aliased) written

#pragma unroll
        for (int mt = 0; mt < 2; ++mt) {
            int lt = wid * 32 + mt * 16 + ml;
            bf16x8 a1 = *(bf16x8*)(Xl + lt * 40 + kb * 8);
            f32x4 c1[8] = {};
#pragma unroll
            for (int nt = 0; nt < 8; ++nt)
                c1[nt] = __builtin_amdgcn_mfma_f32_16x16x32_bf16(a1, w1f[nt], c1[nt], 0, 0, 0);
#pragma unroll
            for (int nt = 0; nt < 8; ++nt) {
#pragma unroll
                for (int r = 0; r < 4; ++r) {
                    int m = kb * 4 + r;
                    int h = nt * 16 + ml;
                    int bo = (m * 256 + h * 2) ^ ((m & 7) << 4);
                    *(short*)((char*)Hw + bo) = f2bf(fmaxf(c1[nt][r], 0.f));
                }
            }
            f32x4 c2[4] = {};
#pragma unroll
            for (int s = 0; s < 4; ++s) {
                int c0 = s * 32 + kb * 8;
                int bo = (ml * 256 + c0 * 2) ^ ((ml & 7) << 4);
                bf16x8 a2 = *(bf16x8*)((char*)Hw + bo);
#pragma unroll
                for (int nt = 0; nt < 4; ++nt)
                    c2[nt] = __builtin_amdgcn_mfma_f32_16x16x32_bf16(a2, w2f[s * 4 + nt], c2[nt], 0, 0, 0);
            }
            float sacc[4] = {0.f, 0.f, 0.f, 0.f};
#pragma unroll
            for (int nt = 0; nt < 4; ++nt) {
#pragma unroll
                for (int r = 0; r < 4; ++r)
                    sacc[r] += fmaxf(c2[nt][r] + b2r[nt], 0.f) * w3r[nt];
            }
#pragma unroll
            for (int o = 1; o < 16; o <<= 1) {
#pragma unroll
                for (int r = 0; r < 4; ++r)
                    sacc[r] += __shfl_xor(sacc[r], o);
            }
            if (ml == 0) {
                int tokb = chunk * 128 + wid * 32 + mt * 16 + kb * 4;
#pragma unroll
                for (int r = 0; r < 4; ++r)
                    out_pred[(tokb + r) * NV + v] = sacc[r] + b3v;
            }
        }
    } else if (bx < 1344) {
        // ---------------- ind ----------------
        int p = bx - 768;
        int i = p / NV, j = p % NV;
        float* red = (float*)L;
        float* wl = (float*)L + 256;
        if (t < IH) {
            wl[t]      = iW1[p * 2 * IH + t];
            wl[32 + t] = iW1[p * 2 * IH + IH + t];
            wl[64 + t] = ib1[p * IH + t];
            wl[96 + t] = iW2[p * IH + t];
        }
        __syncthreads();
        float b2v = ib2[p];
        const float* di_p = dataT + i * NTOK;
        const float* dj_p = dataT + j * NTOK;
        float di[16], dj[16], s[16];
#pragma unroll
        for (int q = 0; q < 16; ++q) {
            di[q] = di_p[q * 256 + t];
            dj[q] = dj_p[q * 256 + t];
            s[q] = b2v;
        }
#pragma unroll 4
        for (int h = 0; h < IH; ++h) {
            float w0 = wl[h], w1 = wl[32 + h], bb = wl[64 + h], w2 = wl[96 + h];
#pragma unroll
            for (int q = 0; q < 16; ++q) {
                float a = fmaf(di[q], w0, fmaf(dj[q], w1, bb));
                a = fmaxf(a, 0.f);
                s[q] = fmaf(a, w2, s[q]);
            }
        }
        float acc = 0.f;
#pragma unroll
        for (int q = 0; q < 16; ++q) acc += 1.f / (1.f + expf(-s[q]));
        __syncthreads();
        red[t] = acc;
        __syncthreads();
        for (int st = 128; st > 0; st >>= 1) {
            if (t < st) red[t] += red[t + st];
            __syncthreads();
        }
        if (t == 0) out_ind[p] = red[0] * (1.f / NTOK);
    } else {
        // ---------------- adj output write (verified adj3 unit) ----------
        float* red = (float*)L;
        const int oo = bx - 1344;
        float a = (t < SH2) ? h2[t] * sW3T[oo * 128 + t] : 0.f;
        a = blk_reduce(a, red, t);
        if (t == 0) {
            float sg = 1.f / (1.f + expf(-(a + sb3[oo])));
            int i = oo / NV, j = oo % NV;
            out_adj[oo] = (j > i) ? sg : 0.f;
        }
    }
}

extern "C" void kernel_launch(void* const* d_in, const int* in_sizes, int n_in,
                              void* d_out, int out_size, void* d_ws, size_t ws_size,
                              hipStream_t stream) {
    const float* data = (const float*)d_in[0];
    const float* sW1 = (const float*)d_in[1];
    const float* sb1 = (const float*)d_in[2];
    const float* sW2 = (const float*)d_in[3];
    const float* sb2 = (const float*)d_in[4];
    const float* sW3 = (const float*)d_in[5];
    const float* sb3 = (const float*)d_in[6];
    const float* mW1 = (const float*)d_in[7];
    const float* mb1 = (const float*)d_in[8];
    const float* mW2 = (const float*)d_in[9];
    const float* mb2 = (const float*)d_in[10];
    const float* mW3 = (const float*)d_in[11];
    const float* mb3 = (const float*)d_in[12];
    const float* iW1 = (const float*)d_in[13];
    const float* ib1 = (const float*)d_in[14];
    const float* iW2 = (const float*)d_in[15];
    const float* ib2 = (const float*)d_in[16];

    float* out = (float*)d_out;
    float* ws = (float*)d_ws;
    float* ws_h1 = ws + 576;
    float* ws_h2 = ws + 832;
    float* ws_scratch = ws + 960;
    float* ws_pS = ws + 1088;
    float* ws_pG = ws + 1280;
    float* ws_dataT = ws + 8192;
    float* ws_sW1T = ws + 106496;
    float* ws_sW2T = ws + 253952;
    float* ws_sW3T = ws + 286720;

    k_prep<<<dim3(582), dim3(256), 0, stream>>>(data, ws_dataT, sW1, sW2, sW3,
                                                ws_sW1T, ws_sW2T, ws_sW3T,
                                                mW1, mW2, iW1, ib1, iW2,
                                                ws_scratch, ws_pS, ws_pG);
    k_adj1<<<dim3(SH1), dim3(256), 0, stream>>>(ws_pG, ws_pS, ws_sW1T, sb1, ws_h1);
    k_adj2<<<dim3(SH2), dim3(256), 0, stream>>>(ws_h1, ws_sW2T, sb2, ws_h2);
    k_predind<<<dim3(768 + NP + NP), dim3(256), 0, stream>>>(
        data, mW1, mb1, mW2, mb2, mW3, mb3, ws_h2, ws_sW3T, sb3,
        out, out + NP, ws_dataT, iW1, ib1, iW2, ib2, out + NP + NTOK * NV);
}